// Round 9
// baseline (814.445 us; speedup 1.0000x reference)
//
#include <hip/hip_runtime.h>

// Problem constants
#define BB   4
#define SS   2048
#define DDIM 1024
#define HH   16
#define DKK  64
#define FFF  2048
#define NTOK (BB * SS)   // 8192

typedef __bf16 bf16x8 __attribute__((ext_vector_type(8)));
typedef float floatx4 __attribute__((ext_vector_type(4)));

__device__ __forceinline__ unsigned short f2bf(float f) {
    union { float f; unsigned u; } v; v.f = f;
    unsigned r = v.u + 0x7fffu + ((v.u >> 16) & 1u);   // RNE
    return (unsigned short)(r >> 16);
}

// pack hi16(a),hi16(b) -> one u32 (bf16 truncation x2 in one v_perm)
__device__ __forceinline__ unsigned pack_bf_trunc(float a, float b) {
    union { float f; unsigned u; } x, y; x.f = a; y.f = b;
    return __builtin_amdgcn_perm(y.u, x.u, 0x07060302u);
}

__device__ __forceinline__ bf16x8 as_frag(uint4 v) {
    union { uint4 u; bf16x8 f; } c; c.u = v; return c.f;
}

__device__ __forceinline__ void async_copy16(const unsigned short* g, unsigned short* l) {
    __builtin_amdgcn_global_load_lds(
        (const __attribute__((address_space(1))) void*)g,
        (__attribute__((address_space(3))) void*)l, 16, 0, 0);
}

// ---------------------------------------------------------------------------
// All six weight transposes fused: fp32 W[K][N] -> bf16 Wt[N][K], 64x64 tiles
// ---------------------------------------------------------------------------
__global__ __launch_bounds__(256) void transpose_all(
    const float* __restrict__ Wq, const float* __restrict__ Wk,
    const float* __restrict__ Wv, const float* __restrict__ Wo,
    const float* __restrict__ fc1, const float* __restrict__ fc2,
    unsigned short* __restrict__ wqkT, unsigned short* __restrict__ wvT,
    unsigned short* __restrict__ woT, unsigned short* __restrict__ fc1T,
    unsigned short* __restrict__ fc2T) {
    __shared__ float tile[64][65];
    int t = blockIdx.x;
    const float* src; unsigned short* dst; int K, N, tl;
    if (t < 256)       { src = Wq;  dst = wqkT;                       K = 1024; N = 1024; tl = t; }
    else if (t < 512)  { src = Wk;  dst = wqkT + (size_t)1024 * 1024; K = 1024; N = 1024; tl = t - 256; }
    else if (t < 768)  { src = Wv;  dst = wvT;                        K = 1024; N = 1024; tl = t - 512; }
    else if (t < 1024) { src = Wo;  dst = woT;                        K = 1024; N = 1024; tl = t - 768; }
    else if (t < 1536) { src = fc1; dst = fc1T;                       K = 1024; N = 2048; tl = t - 1024; }
    else               { src = fc2; dst = fc2T;                       K = 2048; N = 1024; tl = t - 1536; }
    int kt = K >> 6;
    int k0 = (tl & (kt - 1)) * 64, n0 = (tl / kt) * 64;
    int tid = threadIdx.x;
#pragma unroll
    for (int i = 0; i < 16; ++i) {
        int e = i * 256 + tid;
        int r = e >> 6, c = e & 63;
        tile[r][c] = src[(size_t)(k0 + r) * N + (n0 + c)];
    }
    __syncthreads();
#pragma unroll
    for (int i = 0; i < 16; ++i) {
        int e = i * 256 + tid;
        int r = e >> 6, c = e & 63;
        dst[(size_t)(n0 + r) * K + (k0 + c)] = f2bf(tile[c][r]);
    }
}

// ---------------------------------------------------------------------------
// LayerNorm: fp32 in -> bf16 out
// ---------------------------------------------------------------------------
__device__ __forceinline__ float block_sum256(float s) {
#pragma unroll
    for (int o = 32; o > 0; o >>= 1) s += __shfl_xor(s, o);
    __shared__ float partial[4];
    int w = threadIdx.x >> 6;
    __syncthreads();
    if ((threadIdx.x & 63) == 0) partial[w] = s;
    __syncthreads();
    return partial[0] + partial[1] + partial[2] + partial[3];
}

__global__ __launch_bounds__(256) void layernorm_bf16(
    const float* __restrict__ x, const float* __restrict__ g,
    const float* __restrict__ b, unsigned short* __restrict__ out, float eps) {
    size_t row = blockIdx.x;
    const float* xr = x + row * DDIM;
    int tid = threadIdx.x;
    float4 v = *(const float4*)(xr + tid * 4);
    float mu = block_sum256(v.x + v.y + v.z + v.w) * (1.0f / DDIM);
    float dx = v.x - mu, dy = v.y - mu, dz = v.z - mu, dw = v.w - mu;
    float var = block_sum256(dx * dx + dy * dy + dz * dz + dw * dw) * (1.0f / DDIM);
    float rstd = rsqrtf(var + eps);
    int c = tid * 4;
    unsigned short* o = out + row * DDIM + c;
    o[0] = f2bf(dx * rstd * g[c + 0] + b[c + 0]);
    o[1] = f2bf(dy * rstd * g[c + 1] + b[c + 1]);
    o[2] = f2bf(dz * rstd * g[c + 2] + b[c + 2]);
    o[3] = f2bf(dw * rstd * g[c + 3] + b[c + 3]);
}

// ---------------------------------------------------------------------------
// Double-buffered GEMM: A and B both staged via global_load_lds, BK=32,
// TWO LDS buffers each (32 KB total), ONE __syncthreads per iter. The DMA
// for iter k+1 is issued immediately after the barrier, so it has the whole
// compute phase of iter k to land -> barrier drain ~900 -> ~400 cyc.
// 128x128 tile, 4 waves 2x2. XCD m-swizzle: m_tile = bid & 63.
// ---------------------------------------------------------------------------
__global__ __launch_bounds__(256) void gemm_db(
    const unsigned short* __restrict__ A, const unsigned short* __restrict__ Bt,
    const float* __restrict__ bias, const float* __restrict__ resid,
    float* __restrict__ outf, unsigned short* __restrict__ outh,
    int M, int N, int K, int relu) {
    __shared__ unsigned short As[2][128 * 32];
    __shared__ unsigned short Bs[2][128 * 32];
    int tid = threadIdx.x;
    int wave = tid >> 6, lane = tid & 63;
    int lr = lane & 15, quad = lane >> 4;
    int bid = blockIdx.x;
    int m0 = (bid & 63) * 128;         // M == 8192 -> 64 m-tiles
    int n0 = (bid >> 6) * 128;
    int wm = (wave >> 1) * 64, wn = (wave & 1) * 64;

    floatx4 acc[4][4];
#pragma unroll
    for (int i = 0; i < 4; ++i)
#pragma unroll
        for (int t = 0; t < 4; ++t)
#pragma unroll
            for (int r = 0; r < 4; ++r) acc[i][t][r] = 0.0f;

    // staging: 128x32 tile = 2 calls x (256 thr x 16B); thread -> row tid>>2
    int srow = tid >> 2;               // 0..63
    int scol = (tid & 3) * 8;
    const unsigned short* ag0 = A  + (size_t)(m0 + srow) * K + scol;
    const unsigned short* ag1 = A  + (size_t)(m0 + srow + 64) * K + scol;
    const unsigned short* bg0 = Bt + (size_t)(n0 + srow) * K + scol;
    const unsigned short* bg1 = Bt + (size_t)(n0 + srow + 64) * K + scol;
    int l0 = srow * 32 + scol;
    int l1 = (srow + 64) * 32 + scol;

    // prologue: tile 0 -> buffer 0
    async_copy16(ag0, &As[0][l0]);
    async_copy16(ag1, &As[0][l1]);
    async_copy16(bg0, &Bs[0][l0]);
    async_copy16(bg1, &Bs[0][l1]);

    int cur = 0;
    for (int k0 = 0; k0 < K; k0 += 32) {
        __syncthreads();               // drains DMA(cur); readers of cur^1 done
        if (k0 + 32 < K) {
            int nb = cur ^ 1, kn = k0 + 32;
            async_copy16(ag0 + kn, &As[nb][l0]);
            async_copy16(ag1 + kn, &As[nb][l1]);
            async_copy16(bg0 + kn, &Bs[nb][l0]);
            async_copy16(bg1 + kn, &Bs[nb][l1]);
        }
        bf16x8 af[4], bfr[4];
#pragma unroll
        for (int i = 0; i < 4; ++i)
            af[i] = *(const bf16x8*)&As[cur][(wm + 16 * i + lr) * 32 + quad * 8];
#pragma unroll
        for (int t = 0; t < 4; ++t)
            bfr[t] = *(const bf16x8*)&Bs[cur][(wn + 16 * t + lr) * 32 + quad * 8];
#pragma unroll
        for (int i = 0; i < 4; ++i)
#pragma unroll
            for (int t = 0; t < 4; ++t)
                acc[i][t] = __builtin_amdgcn_mfma_f32_16x16x32_bf16(
                    af[i], bfr[t], acc[i][t], 0, 0, 0);
        cur ^= 1;
    }

#pragma unroll
    for (int i = 0; i < 4; ++i) {
#pragma unroll
        for (int t = 0; t < 4; ++t) {
            int col = n0 + wn + 16 * t + lr;
#pragma unroll
            for (int r = 0; r < 4; ++r) {
                int row = m0 + wm + 16 * i + quad * 4 + r;
                float v = acc[i][t][r];
                if (bias)  v += bias[col];
                if (resid) v += resid[(size_t)row * N + col];
                if (relu)  v = fmaxf(v, 0.0f);
                size_t idx = (size_t)row * N + col;
                if (outf) outf[idx] = v;
                else      outh[idx] = f2bf(v);
            }
        }
    }
}

// ---------------------------------------------------------------------------
// V transpose: vb[token][1024] -> vt[bh][dk][s'] with per-64-block
// permutation sigma(u) = 4*(u&15) + (u>>4)  (matches attention P-writes).
// ---------------------------------------------------------------------------
__global__ __launch_bounds__(256) void transpose_v(
    const unsigned short* __restrict__ vb, unsigned short* __restrict__ vt) {
    int bh = blockIdx.y;
    int b = bh >> 4, h = bh & 15;
    int s = blockIdx.x * 256 + threadIdx.x;
    size_t inbase = ((size_t)(b * SS + s)) * DDIM + h * 64;
    size_t outbase = (size_t)bh * 64 * SS;
    int sp = (s & ~63) + 4 * (s & 15) + ((s >> 4) & 3);
#pragma unroll
    for (int dk8 = 0; dk8 < 8; ++dk8) {
        uint4 raw = *(const uint4*)(vb + inbase + dk8 * 8);
        const unsigned short* ph = (const unsigned short*)&raw;
#pragma unroll
        for (int i = 0; i < 8; ++i)
            vt[outbase + (size_t)(dk8 * 8 + i) * SS + sp] = ph[i];
    }
}

// ---------------------------------------------------------------------------
// Flash attention v6 = v5 with Q fragments moved from 32 VGPRs to LDS:
// frees registers (192 -> ~160 total incl. 64 AGPR) so 3 waves/SIMD become
// resident (launch_bounds(256,3)) to hide the direct K/V load latency.
// Barrier-free jt loop otherwise unchanged: K/V direct global->VGPR,
// softmax-lite, wave-private P via LDS, partial O/l merged in epilogue.
// ---------------------------------------------------------------------------
#define PST 68    // Ps row stride (bf16)
#define QST 72    // Qs row stride (bf16)

__global__ __launch_bounds__(256, 3) void attention_mfma6(
    const unsigned short* __restrict__ qk, const unsigned short* __restrict__ vt,
    unsigned short* __restrict__ ctx) {
    __shared__ unsigned short Qs[128 * QST];   // 18432 B
    __shared__ unsigned short Ps[256 * PST];   // 34816 B; reused by epilogue

    int tid = threadIdx.x;
    int wave = tid >> 6, lane = tid & 63;
    int lr = lane & 15, quad = lane >> 4;
    int wq = wave >> 1, wj = wave & 1;

    int bid = blockIdx.x;
    int bh = bid & 63;                 // same bh -> same XCD
    int qt = bid >> 6;
    int b = bh >> 4, h = bh & 15;
    int q0 = qt * 128;
    size_t q_base = ((size_t)b * SS) * 2048 + h * 64;
    size_t k_base = q_base + 1024;
    size_t vt_base = (size_t)bh * 64 * SS;

    // stage Q tile 128x64 into LDS once
#pragma unroll
    for (int i = 0; i < 4; ++i) {
        int e = i * 256 + tid;
        int r = e >> 3, c8 = (e & 7) * 8;
        *(uint4*)&Qs[r * QST + c8] =
            *(const uint4*)(qk + q_base + (size_t)(q0 + r) * 2048 + c8);
    }
    __syncthreads();

    floatx4 o[4][4];
    float l[4][4];
#pragma unroll
    for (int i = 0; i < 4; ++i)
#pragma unroll
        for (int t = 0; t < 4; ++t) {
#pragma unroll
            for (int r = 0; r < 4; ++r) o[i][t][r] = 0.0f;
            l[i][t] = 0.0f;
        }

    unsigned short* myPs = &Ps[wave * 64 * PST];
    const float C = 0.18033688011112042f;   // 0.125 * log2(e)

    for (int jt = 0; jt < SS / 128; ++jt) {
        int j0 = jt * 128 + 64 * wj;

        floatx4 s[4][4];
#pragma unroll
        for (int i = 0; i < 4; ++i)
#pragma unroll
            for (int t = 0; t < 4; ++t)
#pragma unroll
                for (int r = 0; r < 4; ++r) s[i][t][r] = 0.0f;
#pragma unroll
        for (int kk = 0; kk < 2; ++kk) {
            uint4 bv[4];
#pragma unroll
            for (int t = 0; t < 4; ++t)
                bv[t] = *(const uint4*)(qk + k_base +
                    (size_t)(j0 + 16 * t + lr) * 2048 + kk * 32 + quad * 8);
            bf16x8 af[4];
#pragma unroll
            for (int i = 0; i < 4; ++i)
                af[i] = *(const bf16x8*)&Qs[(64 * wq + 16 * i + lr) * QST + kk * 32 + quad * 8];
#pragma unroll
            for (int i = 0; i < 4; ++i)
#pragma unroll
                for (int t = 0; t < 4; ++t)
                    s[i][t] = __builtin_amdgcn_mfma_f32_16x16x32_bf16(
                        af[i], as_frag(bv[t]), s[i][t], 0, 0, 0);
        }

        // softmax-lite + P write (wave-private, sigma-permuted: j=16t+lr -> 4lr+t)
#pragma unroll
        for (int i = 0; i < 4; ++i) {
#pragma unroll
            for (int r = 0; r < 4; ++r) {
                float p0 = exp2f(s[i][0][r] * C);
                float p1 = exp2f(s[i][1][r] * C);
                float p2 = exp2f(s[i][2][r] * C);
                float p3 = exp2f(s[i][3][r] * C);
                l[i][r] += (p0 + p1) + (p2 + p3);
                uint2 w;
                w.x = pack_bf_trunc(p0, p1);
                w.y = pack_bf_trunc(p2, p3);
                *(uint2*)&myPs[(16 * i + quad * 4 + r) * PST + 4 * lr] = w;
            }
        }

        // O += P @ V-half
#pragma unroll
        for (int kk = 0; kk < 2; ++kk) {
            uint4 vv[4];
#pragma unroll
            for (int t = 0; t < 4; ++t)
                vv[t] = *(const uint4*)(vt + vt_base +
                    (size_t)(16 * t + lr) * SS + j0 + kk * 32 + quad * 8);
            bf16x8 pf[4];
#pragma unroll
            for (int i = 0; i < 4; ++i)
                pf[i] = *(const bf16x8*)&myPs[(16 * i + lr) * PST + kk * 32 + quad * 8];
#pragma unroll
            for (int i = 0; i < 4; ++i)
#pragma unroll
                for (int t = 0; t < 4; ++t)
                    o[i][t] = __builtin_amdgcn_mfma_f32_16x16x32_bf16(
                        pf[i], as_frag(vv[t]), o[i][t], 0, 0, 0);
        }
    }

    // reduce l partials across the 16 lanes of each row
#pragma unroll
    for (int i = 0; i < 4; ++i)
#pragma unroll
        for (int r = 0; r < 4; ++r) {
            float ls = l[i][r];
            ls += __shfl_xor(ls, 1);
            ls += __shfl_xor(ls, 2);
            ls += __shfl_xor(ls, 4);
            ls += __shfl_xor(ls, 8);
            l[i][r] = ls;
        }

    // merge j-halves: wj==1 dumps partial O,l to LDS; wj==0 combines+stores
    __syncthreads();
    float* obuf = (float*)Ps;             // [2][64][65] floats
    float* lbuf = obuf + 2 * 64 * 65;     // [2][64] floats
    if (wj == 1) {
#pragma unroll
        for (int i = 0; i < 4; ++i)
#pragma unroll
            for (int r = 0; r < 4; ++r) {
                int rl = 16 * i + quad * 4 + r;
#pragma unroll
                for (int t = 0; t < 4; ++t)
                    obuf[(wq * 64 + rl) * 65 + 16 * t + lr] = o[i][t][r];
                if (lr == 0) lbuf[wq * 64 + rl] = l[i][r];
            }
    }
    __syncthreads();
    if (wj == 0) {
#pragma unroll
        for (int i = 0; i < 4; ++i)
#pragma unroll
            for (int r = 0; r < 4; ++r) {
                int rl = 16 * i + quad * 4 + r;
                float inv = 1.0f / (l[i][r] + lbuf[wq * 64 + rl]);
                int row = q0 + 64 * wq + rl;
                size_t base = ((size_t)(b * SS + row)) * DDIM + h * 64;
#pragma unroll
                for (int t = 0; t < 4; ++t)
                    ctx[base + 16 * t + lr] =
                        f2bf((o[i][t][r] + obuf[(wq * 64 + rl) * 65 + 16 * t + lr]) * inv);
            }
    }
}

// ---------------------------------------------------------------------------
extern "C" void kernel_launch(void* const* d_in, const int* in_sizes, int n_in,
                              void* d_out, int out_size, void* d_ws, size_t ws_size,
                              hipStream_t stream) {
    const float* x     = (const float*)d_in[0];
    const float* Wq    = (const float*)d_in[1];
    const float* Wk    = (const float*)d_in[2];
    const float* Wv    = (const float*)d_in[3];
    const float* Wo    = (const float*)d_in[4];
    const float* ln1g  = (const float*)d_in[5];
    const float* ln1b  = (const float*)d_in[6];
    const float* fc1w  = (const float*)d_in[7];
    const float* fc1b  = (const float*)d_in[8];
    const float* fc2w  = (const float*)d_in[9];
    const float* fc2b  = (const float*)d_in[10];
    const float* ln2g  = (const float*)d_in[11];
    const float* ln2b  = (const float*)d_in[12];
    float* out = (float*)d_out;

    // workspace (peak 80MB):
    //  0..16 : weights (wqkT@0 [2048x1024], wvT@4, woT@6, fc1T@8, fc2T@12)
    // 16..32 : xn -> vt (after V GEMM) -> hn (after attention)
    // 32..64 : qkbuf [8192][2048] -> h1
    // 64..80 : vb -> ctx
    char* ws = (char*)d_ws;
    const size_t MB = 1024 * 1024;
    unsigned short* wqkT = (unsigned short*)(ws + 0 * MB);
    unsigned short* wvT  = (unsigned short*)(ws + 4 * MB);
    unsigned short* woT  = (unsigned short*)(ws + 6 * MB);
    unsigned short* fc1T = (unsigned short*)(ws + 8 * MB);
    unsigned short* fc2T = (unsigned short*)(ws + 12 * MB);
    unsigned short* xn   = (unsigned short*)(ws + 16 * MB);
    unsigned short* vt   = xn;
    unsigned short* hn   = xn;
    unsigned short* qkb  = (unsigned short*)(ws + 32 * MB);
    unsigned short* h1   = qkb;
    unsigned short* vb   = (unsigned short*)(ws + 64 * MB);
    unsigned short* ctx  = vb;

    dim3 blk(256);

    transpose_all<<<2048, blk, 0, stream>>>(Wq, Wk, Wv, Wo, fc1w, fc2w,
                                            wqkT, wvT, woT, fc1T, fc2T);

    layernorm_bf16<<<NTOK, blk, 0, stream>>>(x, ln1g, ln1b, xn, 1e-5f);

    // fused QK projection: N=2048 -> 1024 blocks (1D swizzled grid)
    gemm_db<<<1024, blk, 0, stream>>>(xn, wqkT, nullptr, nullptr, nullptr, qkb, NTOK, 2048, 1024, 0);
    // V projection
    gemm_db<<<512, blk, 0, stream>>>(xn, wvT, nullptr, nullptr, nullptr, vb, NTOK, 1024, 1024, 0);
    transpose_v<<<dim3(8, 64), blk, 0, stream>>>(vb, vt);   // vt overwrites xn

    attention_mfma6<<<1024, blk, 0, stream>>>(qkb, vt, ctx);  // ctx overwrites vb

    gemm_db<<<512, blk, 0, stream>>>(ctx, woT, nullptr, x, out, nullptr, NTOK, 1024, 1024, 0);
    layernorm_bf16<<<NTOK, blk, 0, stream>>>(out, ln2g, ln2b, hn, 1e-6f);
    gemm_db<<<1024, blk, 0, stream>>>(hn, fc1T, fc1b, nullptr, nullptr, h1, NTOK, 2048, 1024, 1);
    gemm_db<<<512, blk, 0, stream>>>(h1, fc2T, fc2b, out, out, nullptr, NTOK, 1024, 2048, 0);
}

// Round 10
// 534.237 us; speedup vs baseline: 1.5245x; 1.5245x over previous
//
#include <hip/hip_runtime.h>

// Problem constants
#define BB   4
#define SS   2048
#define DDIM 1024
#define HH   16
#define DKK  64
#define FFF  2048
#define NTOK (BB * SS)   // 8192
#define QKVS 3072        // fused qkv row stride
#define SCALE_Q 0.18033688011112042f   // 0.125 * log2(e), folded into Q

typedef __bf16 bf16x8 __attribute__((ext_vector_type(8)));
typedef float floatx4 __attribute__((ext_vector_type(4)));

__device__ __forceinline__ unsigned short f2bf(float f) {
    union { float f; unsigned u; } v; v.f = f;
    unsigned r = v.u + 0x7fffu + ((v.u >> 16) & 1u);   // RNE
    return (unsigned short)(r >> 16);
}

// pack hi16(a),hi16(b) -> one u32 (bf16 truncation x2 in one v_perm)
__device__ __forceinline__ unsigned pack_bf_trunc(float a, float b) {
    union { float f; unsigned u; } x, y; x.f = a; y.f = b;
    return __builtin_amdgcn_perm(y.u, x.u, 0x07060302u);
}

__device__ __forceinline__ bf16x8 as_frag(uint4 v) {
    union { uint4 u; bf16x8 f; } c; c.u = v; return c.f;
}

__device__ __forceinline__ void async_copy16(const unsigned short* g, unsigned short* l) {
    __builtin_amdgcn_global_load_lds(
        (const __attribute__((address_space(1))) void*)g,
        (__attribute__((address_space(3))) void*)l, 16, 0, 0);
}

// ---------------------------------------------------------------------------
// All six weight transposes fused: fp32 W[K][N] -> bf16 Wt[N][K], 64x64 tiles
// Wq/Wk/Wv land in one contiguous wqkvT [3072][1024].
// ---------------------------------------------------------------------------
__global__ __launch_bounds__(256) void transpose_all(
    const float* __restrict__ Wq, const float* __restrict__ Wk,
    const float* __restrict__ Wv, const float* __restrict__ Wo,
    const float* __restrict__ fc1, const float* __restrict__ fc2,
    unsigned short* __restrict__ wqkvT, unsigned short* __restrict__ woT,
    unsigned short* __restrict__ fc1T, unsigned short* __restrict__ fc2T) {
    __shared__ float tile[64][65];
    int t = blockIdx.x;
    const float* src; unsigned short* dst; int K, N, tl;
    if (t < 256)       { src = Wq;  dst = wqkvT;                       K = 1024; N = 1024; tl = t; }
    else if (t < 512)  { src = Wk;  dst = wqkvT + (size_t)1024 * 1024; K = 1024; N = 1024; tl = t - 256; }
    else if (t < 768)  { src = Wv;  dst = wqkvT + (size_t)2048 * 1024; K = 1024; N = 1024; tl = t - 512; }
    else if (t < 1024) { src = Wo;  dst = woT;                         K = 1024; N = 1024; tl = t - 768; }
    else if (t < 1536) { src = fc1; dst = fc1T;                        K = 1024; N = 2048; tl = t - 1024; }
    else               { src = fc2; dst = fc2T;                        K = 2048; N = 1024; tl = t - 1536; }
    int kt = K >> 6;
    int k0 = (tl & (kt - 1)) * 64, n0 = (tl / kt) * 64;
    int tid = threadIdx.x;
#pragma unroll
    for (int i = 0; i < 16; ++i) {
        int e = i * 256 + tid;
        int r = e >> 6, c = e & 63;
        tile[r][c] = src[(size_t)(k0 + r) * N + (n0 + c)];
    }
    __syncthreads();
#pragma unroll
    for (int i = 0; i < 16; ++i) {
        int e = i * 256 + tid;
        int r = e >> 6, c = e & 63;
        dst[(size_t)(n0 + r) * K + (k0 + c)] = f2bf(tile[c][r]);
    }
}

// ---------------------------------------------------------------------------
// LayerNorm: fp32 in -> bf16 out
// ---------------------------------------------------------------------------
__device__ __forceinline__ float block_sum256(float s) {
#pragma unroll
    for (int o = 32; o > 0; o >>= 1) s += __shfl_xor(s, o);
    __shared__ float partial[4];
    int w = threadIdx.x >> 6;
    __syncthreads();
    if ((threadIdx.x & 63) == 0) partial[w] = s;
    __syncthreads();
    return partial[0] + partial[1] + partial[2] + partial[3];
}

__global__ __launch_bounds__(256) void layernorm_bf16(
    const float* __restrict__ x, const float* __restrict__ g,
    const float* __restrict__ b, unsigned short* __restrict__ out, float eps) {
    size_t row = blockIdx.x;
    const float* xr = x + row * DDIM;
    int tid = threadIdx.x;
    float4 v = *(const float4*)(xr + tid * 4);
    float mu = block_sum256(v.x + v.y + v.z + v.w) * (1.0f / DDIM);
    float dx = v.x - mu, dy = v.y - mu, dz = v.z - mu, dw = v.w - mu;
    float var = block_sum256(dx * dx + dy * dy + dz * dz + dw * dw) * (1.0f / DDIM);
    float rstd = rsqrtf(var + eps);
    int c = tid * 4;
    unsigned short* o = out + row * DDIM + c;
    o[0] = f2bf(dx * rstd * g[c + 0] + b[c + 0]);
    o[1] = f2bf(dy * rstd * g[c + 1] + b[c + 1]);
    o[2] = f2bf(dz * rstd * g[c + 2] + b[c + 2]);
    o[3] = f2bf(dw * rstd * g[c + 3] + b[c + 3]);
}

// ---------------------------------------------------------------------------
// Double-buffered GEMM (r9 structure, kept): A and B staged via
// global_load_lds, BK=32, two LDS buffers each, ONE barrier per iter with
// next-iter DMA issued right after it. 128x128 tile, 4 waves 2x2.
// XCD m-swizzle (m_tile = bid & 63). New: lda (A row stride) and qcols
// (cols < qcols scaled by SCALE_Q in the epilogue -- folds the attention
// score scale into Q at zero cost).
// ---------------------------------------------------------------------------
__global__ __launch_bounds__(256) void gemm_db(
    const unsigned short* __restrict__ A, const unsigned short* __restrict__ Bt,
    const float* __restrict__ bias, const float* __restrict__ resid,
    float* __restrict__ outf, unsigned short* __restrict__ outh,
    int M, int N, int K, int relu, int lda, int qcols) {
    __shared__ unsigned short As[2][128 * 32];
    __shared__ unsigned short Bs[2][128 * 32];
    int tid = threadIdx.x;
    int wave = tid >> 6, lane = tid & 63;
    int lr = lane & 15, quad = lane >> 4;
    int bid = blockIdx.x;
    int m0 = (bid & 63) * 128;         // M == 8192 -> 64 m-tiles
    int n0 = (bid >> 6) * 128;
    int wm = (wave >> 1) * 64, wn = (wave & 1) * 64;

    floatx4 acc[4][4];
#pragma unroll
    for (int i = 0; i < 4; ++i)
#pragma unroll
        for (int t = 0; t < 4; ++t)
#pragma unroll
            for (int r = 0; r < 4; ++r) acc[i][t][r] = 0.0f;

    int srow = tid >> 2;               // 0..63
    int scol = (tid & 3) * 8;
    const unsigned short* ag0 = A  + (size_t)(m0 + srow) * lda + scol;
    const unsigned short* ag1 = A  + (size_t)(m0 + srow + 64) * lda + scol;
    const unsigned short* bg0 = Bt + (size_t)(n0 + srow) * K + scol;
    const unsigned short* bg1 = Bt + (size_t)(n0 + srow + 64) * K + scol;
    int l0 = srow * 32 + scol;
    int l1 = (srow + 64) * 32 + scol;

    async_copy16(ag0, &As[0][l0]);
    async_copy16(ag1, &As[0][l1]);
    async_copy16(bg0, &Bs[0][l0]);
    async_copy16(bg1, &Bs[0][l1]);

    int cur = 0;
    for (int k0 = 0; k0 < K; k0 += 32) {
        __syncthreads();
        if (k0 + 32 < K) {
            int nb = cur ^ 1, kn = k0 + 32;
            async_copy16(ag0 + kn, &As[nb][l0]);
            async_copy16(ag1 + kn, &As[nb][l1]);
            async_copy16(bg0 + kn, &Bs[nb][l0]);
            async_copy16(bg1 + kn, &Bs[nb][l1]);
        }
        bf16x8 af[4], bfr[4];
#pragma unroll
        for (int i = 0; i < 4; ++i)
            af[i] = *(const bf16x8*)&As[cur][(wm + 16 * i + lr) * 32 + quad * 8];
#pragma unroll
        for (int t = 0; t < 4; ++t)
            bfr[t] = *(const bf16x8*)&Bs[cur][(wn + 16 * t + lr) * 32 + quad * 8];
#pragma unroll
        for (int i = 0; i < 4; ++i)
#pragma unroll
            for (int t = 0; t < 4; ++t)
                acc[i][t] = __builtin_amdgcn_mfma_f32_16x16x32_bf16(
                    af[i], bfr[t], acc[i][t], 0, 0, 0);
        cur ^= 1;
    }

#pragma unroll
    for (int i = 0; i < 4; ++i) {
#pragma unroll
        for (int t = 0; t < 4; ++t) {
            int col = n0 + wn + 16 * t + lr;
            float cs = (col < qcols) ? SCALE_Q : 1.0f;
#pragma unroll
            for (int r = 0; r < 4; ++r) {
                int row = m0 + wm + 16 * i + quad * 4 + r;
                float v = acc[i][t][r];
                if (bias)  v += bias[col];
                if (resid) v += resid[(size_t)row * N + col];
                if (relu)  v = fmaxf(v, 0.0f);
                v *= cs;
                size_t idx = (size_t)row * N + col;
                if (outf) outf[idx] = v;
                else      outh[idx] = f2bf(v);
            }
        }
    }
}

// ---------------------------------------------------------------------------
// V transpose: vsrc rows (stride QKVS) -> vt[bh][dk][s'] with per-64-block
// permutation sigma(u) = 4*(u&15) + (u>>4)  (matches attention P-writes).
// ---------------------------------------------------------------------------
__global__ __launch_bounds__(256) void transpose_v(
    const unsigned short* __restrict__ vsrc, unsigned short* __restrict__ vt) {
    int bh = blockIdx.y;
    int b = bh >> 4, h = bh & 15;
    int s = blockIdx.x * 256 + threadIdx.x;
    size_t inbase = ((size_t)(b * SS + s)) * QKVS + h * 64;
    size_t outbase = (size_t)bh * 64 * SS;
    int sp = (s & ~63) + 4 * (s & 15) + ((s >> 4) & 3);
#pragma unroll
    for (int dk8 = 0; dk8 < 8; ++dk8) {
        uint4 raw = *(const uint4*)(vsrc + inbase + dk8 * 8);
        const unsigned short* ph = (const unsigned short*)&raw;
#pragma unroll
        for (int i = 0; i < 8; ++i)
            vt[outbase + (size_t)(dk8 * 8 + i) * SS + sp] = ph[i];
    }
}

// ---------------------------------------------------------------------------
// Flash attention v7 = r8's v5 (152 us, no spill: launch_bounds(256,2),
// Q-frags in registers) + two VALU cuts:
//  - score scale pre-folded into Q by the projection GEMM  -> p = exp2(s)
//  - s zero-init via hoisted zero C-tuple on the first QK MFMA
// ctx is written into the dead V-columns of the qkv buffer (stride QKVS).
// ---------------------------------------------------------------------------
#define PST 68    // Ps row stride (bf16)

__global__ __launch_bounds__(256, 2) void attention_mfma7(
    const unsigned short* __restrict__ qkv, const unsigned short* __restrict__ vt,
    unsigned short* __restrict__ ctx /* = qkv + 2048, stride QKVS */) {
    __shared__ unsigned short Ps[256 * PST];   // 34816 B; reused by epilogue

    int tid = threadIdx.x;
    int wave = tid >> 6, lane = tid & 63;
    int lr = lane & 15, quad = lane >> 4;
    int wq = wave >> 1, wj = wave & 1;

    int bid = blockIdx.x;
    int bh = bid & 63;                 // same bh -> same XCD
    int qt = bid >> 6;
    int b = bh >> 4, h = bh & 15;
    int q0 = qt * 128;
    size_t q_base = ((size_t)b * SS) * QKVS + h * 64;
    size_t k_base = q_base + 1024;
    size_t vt_base = (size_t)bh * 64 * SS;

    // preload Q A-frags (Q already carries SCALE_Q)
    uint4 af[4][2];
#pragma unroll
    for (int i = 0; i < 4; ++i)
#pragma unroll
        for (int kk = 0; kk < 2; ++kk)
            af[i][kk] = *(const uint4*)(qkv + q_base +
                (size_t)(q0 + 64 * wq + 16 * i + lr) * QKVS + kk * 32 + quad * 8);

    floatx4 o[4][4];
    float l[4][4];
#pragma unroll
    for (int i = 0; i < 4; ++i)
#pragma unroll
        for (int t = 0; t < 4; ++t) {
#pragma unroll
            for (int r = 0; r < 4; ++r) o[i][t][r] = 0.0f;
            l[i][t] = 0.0f;
        }
    floatx4 zf;
#pragma unroll
    for (int r = 0; r < 4; ++r) zf[r] = 0.0f;

    unsigned short* myPs = &Ps[wave * 64 * PST];

    for (int jt = 0; jt < SS / 128; ++jt) {
        int j0 = jt * 128 + 64 * wj;

        // S = Q K^T : kk=0 writes (zero C), kk=1 accumulates
        floatx4 s[4][4];
        {
            uint4 bv[4];
#pragma unroll
            for (int t = 0; t < 4; ++t)
                bv[t] = *(const uint4*)(qkv + k_base +
                    (size_t)(j0 + 16 * t + lr) * QKVS + quad * 8);
#pragma unroll
            for (int i = 0; i < 4; ++i)
#pragma unroll
                for (int t = 0; t < 4; ++t)
                    s[i][t] = __builtin_amdgcn_mfma_f32_16x16x32_bf16(
                        as_frag(af[i][0]), as_frag(bv[t]), zf, 0, 0, 0);
        }
        {
            uint4 bv[4];
#pragma unroll
            for (int t = 0; t < 4; ++t)
                bv[t] = *(const uint4*)(qkv + k_base +
                    (size_t)(j0 + 16 * t + lr) * QKVS + 32 + quad * 8);
#pragma unroll
            for (int i = 0; i < 4; ++i)
#pragma unroll
                for (int t = 0; t < 4; ++t)
                    s[i][t] = __builtin_amdgcn_mfma_f32_16x16x32_bf16(
                        as_frag(af[i][1]), as_frag(bv[t]), s[i][t], 0, 0, 0);
        }

        // softmax-lite: p = exp2(s) directly; wave-private P write
#pragma unroll
        for (int i = 0; i < 4; ++i) {
#pragma unroll
            for (int r = 0; r < 4; ++r) {
                float p0 = exp2f(s[i][0][r]);
                float p1 = exp2f(s[i][1][r]);
                float p2 = exp2f(s[i][2][r]);
                float p3 = exp2f(s[i][3][r]);
                l[i][r] += (p0 + p1) + (p2 + p3);
                uint2 w;
                w.x = pack_bf_trunc(p0, p1);
                w.y = pack_bf_trunc(p2, p3);
                *(uint2*)&myPs[(16 * i + quad * 4 + r) * PST + 4 * lr] = w;
            }
        }

        // O += P @ V-half
#pragma unroll
        for (int kk = 0; kk < 2; ++kk) {
            uint4 vv[4];
#pragma unroll
            for (int t = 0; t < 4; ++t)
                vv[t] = *(const uint4*)(vt + vt_base +
                    (size_t)(16 * t + lr) * SS + j0 + kk * 32 + quad * 8);
            bf16x8 pf[4];
#pragma unroll
            for (int i = 0; i < 4; ++i)
                pf[i] = *(const bf16x8*)&myPs[(16 * i + lr) * PST + kk * 32 + quad * 8];
#pragma unroll
            for (int i = 0; i < 4; ++i)
#pragma unroll
                for (int t = 0; t < 4; ++t)
                    o[i][t] = __builtin_amdgcn_mfma_f32_16x16x32_bf16(
                        pf[i], as_frag(vv[t]), o[i][t], 0, 0, 0);
        }
    }

    // reduce l partials across the 16 lanes of each row
#pragma unroll
    for (int i = 0; i < 4; ++i)
#pragma unroll
        for (int r = 0; r < 4; ++r) {
            float ls = l[i][r];
            ls += __shfl_xor(ls, 1);
            ls += __shfl_xor(ls, 2);
            ls += __shfl_xor(ls, 4);
            ls += __shfl_xor(ls, 8);
            l[i][r] = ls;
        }

    // merge j-halves: wj==1 dumps partial O,l to LDS; wj==0 combines+stores
    __syncthreads();
    float* obuf = (float*)Ps;             // [2][64][65] floats
    float* lbuf = obuf + 2 * 64 * 65;     // [2][64] floats
    if (wj == 1) {
#pragma unroll
        for (int i = 0; i < 4; ++i)
#pragma unroll
            for (int r = 0; r < 4; ++r) {
                int rl = 16 * i + quad * 4 + r;
#pragma unroll
                for (int t = 0; t < 4; ++t)
                    obuf[(wq * 64 + rl) * 65 + 16 * t + lr] = o[i][t][r];
                if (lr == 0) lbuf[wq * 64 + rl] = l[i][r];
            }
    }
    __syncthreads();
    if (wj == 0) {
#pragma unroll
        for (int i = 0; i < 4; ++i)
#pragma unroll
            for (int r = 0; r < 4; ++r) {
                int rl = 16 * i + quad * 4 + r;
                float inv = 1.0f / (l[i][r] + lbuf[wq * 64 + rl]);
                int row = q0 + 64 * wq + rl;
                size_t base = ((size_t)(b * SS + row)) * QKVS + h * 64;
#pragma unroll
                for (int t = 0; t < 4; ++t)
                    ctx[base + 16 * t + lr] =
                        f2bf((o[i][t][r] + obuf[(wq * 64 + rl) * 65 + 16 * t + lr]) * inv);
            }
    }
}

// ---------------------------------------------------------------------------
extern "C" void kernel_launch(void* const* d_in, const int* in_sizes, int n_in,
                              void* d_out, int out_size, void* d_ws, size_t ws_size,
                              hipStream_t stream) {
    const float* x     = (const float*)d_in[0];
    const float* Wq    = (const float*)d_in[1];
    const float* Wk    = (const float*)d_in[2];
    const float* Wv    = (const float*)d_in[3];
    const float* Wo    = (const float*)d_in[4];
    const float* ln1g  = (const float*)d_in[5];
    const float* ln1b  = (const float*)d_in[6];
    const float* fc1w  = (const float*)d_in[7];
    const float* fc1b  = (const float*)d_in[8];
    const float* fc2w  = (const float*)d_in[9];
    const float* fc2b  = (const float*)d_in[10];
    const float* ln2g  = (const float*)d_in[11];
    const float* ln2b  = (const float*)d_in[12];
    float* out = (float*)d_out;

    // workspace (peak 80MB):
    //  0..16 : weights (wqkvT@0 [3072x1024] 6MB, woT@6, fc1T@8, fc2T@12)
    // 16..32 : xn -> vt (after QKV GEMM) -> hn (after attention)
    // 32..80 : qkvb [8192][3072] 48MB; ctx lives in its V-cols (2048..3071)
    //          after transpose_v consumes them; h1 [8192][2048] overlays
    //          bytes 32..64MB once ctx is dead (after Wo GEMM).
    char* ws = (char*)d_ws;
    const size_t MB = 1024 * 1024;
    unsigned short* wqkvT = (unsigned short*)(ws + 0 * MB);
    unsigned short* woT   = (unsigned short*)(ws + 6 * MB);
    unsigned short* fc1T  = (unsigned short*)(ws + 8 * MB);
    unsigned short* fc2T  = (unsigned short*)(ws + 12 * MB);
    unsigned short* xn    = (unsigned short*)(ws + 16 * MB);
    unsigned short* vt    = xn;
    unsigned short* hn    = xn;
    unsigned short* qkvb  = (unsigned short*)(ws + 32 * MB);
    unsigned short* ctx   = qkvb + 2048;        // V-cols, stride QKVS
    unsigned short* h1    = qkvb;               // reuse after ctx dead

    dim3 blk(256);

    transpose_all<<<2048, blk, 0, stream>>>(Wq, Wk, Wv, Wo, fc1w, fc2w,
                                            wqkvT, woT, fc1T, fc2T);

    layernorm_bf16<<<NTOK, blk, 0, stream>>>(x, ln1g, ln1b, xn, 1e-5f);

    // fused QKV projection: N=3072 -> 64*24 = 1536 blocks; Q cols pre-scaled
    gemm_db<<<1536, blk, 0, stream>>>(xn, wqkvT, nullptr, nullptr, nullptr,
                                      qkvb, NTOK, QKVS, 1024, 0, 1024, 1024);
    transpose_v<<<dim3(8, 64), blk, 0, stream>>>(qkvb + 2048, vt);  // vt over xn

    attention_mfma7<<<1024, blk, 0, stream>>>(qkvb, vt, ctx);

    // Wo GEMM reads ctx (stride QKVS) -> fp32 out with residual x
    gemm_db<<<512, blk, 0, stream>>>(ctx, woT, nullptr, x, out, nullptr,
                                     NTOK, 1024, 1024, 0, QKVS, 0);
    layernorm_bf16<<<NTOK, blk, 0, stream>>>(out, ln2g, ln2b, hn, 1e-6f);
    gemm_db<<<1024, blk, 0, stream>>>(hn, fc1T, fc1b, nullptr, nullptr, h1,
                                      NTOK, 2048, 1024, 1, 1024, 0);
    gemm_db<<<512, blk, 0, stream>>>(h1, fc2T, fc2b, out, out, nullptr,
                                     NTOK, 1024, 2048, 0, 2048, 0);
}